// Round 4
// baseline (56.232 us; speedup 1.0000x reference)
//
#include <hip/hip_runtime.h>
#include <hip/hip_bf16.h>

#define R      1000
#define K      80
#define KP1    81
#define CAND   100
#define NC     (K*CAND)
#define VCAP   256
#define SCORE_THRESH 0.05f
#define NMS_THRESH   0.5f

typedef unsigned long long u64;

__device__ __forceinline__ unsigned int ordf(float f) {
    unsigned int u = __float_as_uint(f);
    return (u & 0x80000000u) ? ~u : (u | 0x80000000u);
}
__device__ __forceinline__ float unordf(unsigned int o) {
    unsigned int u = (o & 0x80000000u) ? (o ^ 0x80000000u) : ~o;
    return __uint_as_float(u);
}

// ---------------------------------------------------------------------------
// Kernel 1: fully-coalesced score scan; append packed keys per class.
// key = (ordf(score) << 32) | (0xFFFFFFFF - row)  -> sort gives (score desc,
// row asc) == jnp.argsort(-s) stable order. Append order irrelevant.
// ---------------------------------------------------------------------------
__global__ __launch_bounds__(256) void gather_kernel(
    const float* __restrict__ scores,     // (R, 81)
    unsigned* __restrict__ cnt,           // [K]
    u64* __restrict__ key_stage)          // [K][VCAP]
{
    const int t = blockIdx.x * 256 + threadIdx.x;
    const int idx4 = t * 4;
    if (idx4 >= R * KP1) return;          // 81000 = 4*20250, exact float4s
    const float4 sv = *(const float4*)(scores + idx4);
    #pragma unroll
    for (int e = 0; e < 4; ++e) {
        const int idx = idx4 + e;
        const float s = (e == 0) ? sv.x : (e == 1) ? sv.y : (e == 2) ? sv.z : sv.w;
        const int row = idx / KP1;        // compiler magic-mul
        const int col = idx - row * KP1;
        if (col < K && s > SCORE_THRESH) {
            unsigned slot = atomicAdd(&cnt[col], 1u);
            if (slot < VCAP)
                key_stage[col * VCAP + slot] =
                    ((u64)ordf(s) << 32) | (u64)(0xFFFFFFFFu - (unsigned)row);
        }
    }
}

// ---------------------------------------------------------------------------
// Kernel 2: one wave per class. Register bitonic sort -> box gather+clip ->
// merged IoU+greedy scan with UNIFORM scalar kept-masks -> emit candidates.
// ---------------------------------------------------------------------------
template<int NR>
__device__ __forceinline__ void sort_nms_emit(
    int k, int lane, int n,
    const float* __restrict__ boxes, float Wf, float Hf,
    const u64* __restrict__ key_stage,
    u64* __restrict__ cand_key, float4* __restrict__ cand_box,
    float4* sbox)
{
    const u64 lt_mask = (1ull << lane) - 1ull;
    u64 key[NR];
    #pragma unroll
    for (int r = 0; r < NR; ++r) {
        int i = r * 64 + lane;
        key[r] = (i < n) ? key_stage[k * VCAP + i] : 0ull;
    }

    constexpr int N = NR * 64;
    // ---- bitonic sort, descending, keys in registers (proven in R3)
    #pragma unroll
    for (int size = 2; size <= N; size <<= 1) {
        #pragma unroll
        for (int stride = size >> 1; stride > 0; stride >>= 1) {
            if (stride >= 64) {
                const int rs = stride >> 6;
                #pragma unroll
                for (int r = 0; r < NR; ++r) {
                    if ((r & rs) == 0 && (r | rs) < NR) {
                        const int r2 = r | rs;
                        const bool desc = (((r * 64) & size) == 0);
                        u64 a = key[r], b = key[r2];
                        bool sw = desc ? (a < b) : (a > b);
                        if (sw) { key[r] = b; key[r2] = a; }
                    }
                }
            } else {
                #pragma unroll
                for (int r = 0; r < NR; ++r) {
                    u64 part = __shfl_xor(key[r], stride, 64);
                    bool desc = (((r * 64 + lane) & size) == 0);
                    bool lower = ((lane & stride) == 0);
                    bool takeMax = (lower == desc);
                    bool pgt = part > key[r];
                    key[r] = (takeMax == pgt) ? part : key[r];
                }
            }
        }
    }

    // ---- gather + clip boxes of sorted entries; stage to LDS for broadcast
    float4 bx[NR]; float sc[NR]; float area[NR];
    #pragma unroll
    for (int r = 0; r < NR; ++r) {
        int i = r * 64 + lane;
        u64 kk = key[r];
        sc[r] = unordf((unsigned)(kk >> 32));
        unsigned row = 0xFFFFFFFFu - (unsigned)kk;
        float4 bb = make_float4(0.f, 0.f, 0.f, 0.f);
        if (i < n) {
            bb = *(const float4*)(boxes + (size_t)row * (K * 4) + (size_t)k * 4);
            bb.x = fminf(fmaxf(bb.x, 0.f), Wf);
            bb.y = fminf(fmaxf(bb.y, 0.f), Hf);
            bb.z = fminf(fmaxf(bb.z, 0.f), Wf);
            bb.w = fminf(fmaxf(bb.w, 0.f), Hf);
        }
        bx[r] = bb;
        area[r] = (bb.z - bb.x) * (bb.w - bb.y);
        sbox[i] = bb;            // single wave: in-order LDS, no barrier
    }

    // ---- merged IoU + greedy scan. kept[] is wave-UNIFORM (scalar) so the
    // loop-carried chain is ballot -> s_and/s_or only; FP IoU pipelines free.
    u64 kept[NR];
    #pragma unroll
    for (int r = 0; r < NR; ++r) kept[r] = 0ull;

    #pragma unroll
    for (int jc = 0; jc < NR; ++jc) {
        int jmax = n - jc * 64;
        if (jmax > 64) jmax = 64;
        for (int jl = 0; jl < jmax; ++jl) {
            float4 bj = sbox[jc * 64 + jl];
            float areaB = (bj.z - bj.x) * (bj.w - bj.y);
            u64 hit = 0ull;
            #pragma unroll
            for (int r = 0; r < NR; ++r) {
                float ltx = fmaxf(bx[r].x, bj.x), lty = fmaxf(bx[r].y, bj.y);
                float rbx = fminf(bx[r].z, bj.z), rby = fminf(bx[r].w, bj.w);
                float w = fmaxf(rbx - ltx, 0.f), h = fmaxf(rby - lty, 0.f);
                float inter = w * h;
                float uni = area[r] + areaB - inter;
                float iou = inter / fmaxf(uni, 1e-9f);   // bit-identical to ref
                u64 ball = __ballot(iou > NMS_THRESH);
                hit |= ball & kept[r];
            }
            if (hit == 0ull) kept[jc] |= (1ull << jl);   // uniform update
        }
    }

    // ---- emit kept candidates in rank order; zero-key fillers
    unsigned pre = 0;
    u64* ck = cand_key + (size_t)k * CAND;
    float4* cb = cand_box + (size_t)k * CAND;
    #pragma unroll
    for (int r = 0; r < NR; ++r) {
        u64 m = kept[r];
        bool mine = (m >> lane) & 1ull;
        unsigned rank = pre + (unsigned)__popcll(m & lt_mask);
        if (mine && rank < CAND) {
            unsigned c = (unsigned)(k * CAND + rank);
            ck[rank] = ((u64)ordf(sc[r]) << 32) | (u64)(0xFFFFFFFFu - c);
            cb[rank] = bx[r];
        }
        pre += (unsigned)__popcll(m);
    }
    unsigned T100 = pre < CAND ? pre : CAND;
    for (unsigned s2 = T100 + (unsigned)lane; s2 < CAND; s2 += 64) ck[s2] = 0ull;
}

__global__ __launch_bounds__(64) void nms_kernel(
    const float* __restrict__ boxes,
    const int* __restrict__ imh, const int* __restrict__ imw,
    const unsigned* __restrict__ cnt, const u64* __restrict__ key_stage,
    u64* __restrict__ cand_key, float4* __restrict__ cand_box)
{
    __shared__ float4 sbox[VCAP];
    const int k = blockIdx.x, lane = threadIdx.x;
    int n = (int)cnt[k];
    if (n > VCAP) n = VCAP;
    const float Wf = (float)(*imw), Hf = (float)(*imh);

    if (n == 0) {
        for (int s2 = lane; s2 < CAND; s2 += 64) cand_key[(size_t)k * CAND + s2] = 0ull;
        return;
    }
    if (n <= 64)       sort_nms_emit<1>(k, lane, n, boxes, Wf, Hf, key_stage, cand_key, cand_box, sbox);
    else if (n <= 128) sort_nms_emit<2>(k, lane, n, boxes, Wf, Hf, key_stage, cand_key, cand_box, sbox);
    else               sort_nms_emit<4>(k, lane, n, boxes, Wf, Hf, key_stage, cand_key, cand_box, sbox);
}

// ---------------------------------------------------------------------------
// Kernel 3: exact top-100 of 8000 distinct u64 keys via MSB-first radix
// select (keys in registers), then O(100^2) ranking. Proven in R3.
// ---------------------------------------------------------------------------
__global__ __launch_bounds__(256) void topk_kernel(
    const u64* __restrict__ cand_key,
    const float4* __restrict__ cand_box,
    float* __restrict__ out)   // [0..499]=dets (100x5), [500..599]=classes
{
    const int tid  = threadIdx.x;
    const int lane = tid & 63;
    const int w    = tid >> 6;

    __shared__ unsigned hist[4][264];
    __shared__ unsigned wsum[4];
    __shared__ u64 Psh;
    __shared__ unsigned remsh, cntsh;
    __shared__ u64 Wl[128];

    u64 keyv[32];
    #pragma unroll
    for (int j = 0; j < 32; ++j) {
        int idx = tid + 256 * j;
        keyv[j] = (idx < NC) ? cand_key[idx] : 0ull;
    }
    if (tid == 0) { Psh = 0ull; remsh = CAND - 1; cntsh = 0; }

    // bits 31..16 of every nonzero key are 0xFFFF (candidate id < 8192):
    // skip passes 3,2; patch prefix after pass 4.
    const int plist[6] = {7, 6, 5, 4, 1, 0};
    for (int pi = 0; pi < 6; ++pi) {
        const int p = plist[pi];
        const int shift = 8 * p;
        #pragma unroll
        for (int ww = 0; ww < 4; ++ww) hist[ww][tid] = 0;
        __syncthreads();

        u64 pfx = Psh;
        unsigned rem = remsh;
        u64 hmask = (p == 7) ? 0ull : (~0ull << (shift + 8));
        #pragma unroll
        for (int j = 0; j < 32; ++j) {
            u64 kk = keyv[j];
            if (kk != 0ull && ((kk ^ pfx) & hmask) == 0ull)
                atomicAdd(&hist[w][(unsigned)(kk >> shift) & 0xFFu], 1u);
        }
        __syncthreads();

        int b = 255 - tid;
        unsigned v = hist[0][b] + hist[1][b] + hist[2][b] + hist[3][b];
        unsigned inc = v;
        #pragma unroll
        for (int off = 1; off < 64; off <<= 1) {
            unsigned t2 = __shfl_up(inc, off);
            if (lane >= off) inc += t2;
        }
        if (lane == 63) wsum[w] = inc;
        __syncthreads();
        unsigned woff = 0;
        #pragma unroll
        for (int ww = 0; ww < 4; ++ww) if (ww < w) woff += wsum[ww];
        inc += woff;
        unsigned cumG = inc - v;
        if (v > 0 && rem >= cumG && rem < cumG + v) {
            u64 np = pfx | ((u64)(unsigned)b << shift);
            if (p == 4) np |= 0xFFFF0000ull;
            Psh = np;
            remsh = rem - cumG;
        }
        __syncthreads();
    }

    const u64 T = Psh;   // exact rank-99 key
    #pragma unroll
    for (int j = 0; j < 32; ++j) {
        u64 kk = keyv[j];
        if (kk >= T && kk != 0ull) {
            unsigned pos = atomicAdd(&cntsh, 1u);
            if (pos < 128) Wl[pos] = kk;
        }
    }
    __syncthreads();

    if (tid < CAND) {
        u64 my = Wl[tid];
        int r = 0;
        for (int j = 0; j < CAND; ++j) r += (Wl[j] > my) ? 1 : 0;
        unsigned c = 0xFFFFFFFFu - (unsigned)my;
        float s = unordf((unsigned)(my >> 32));
        float4 bb = cand_box[c];
        out[r * 5 + 0] = bb.x;
        out[r * 5 + 1] = bb.y;
        out[r * 5 + 2] = bb.z;
        out[r * 5 + 3] = bb.w;
        out[r * 5 + 4] = s;
        out[500 + r]   = (float)(c / CAND);
    }
}

extern "C" void kernel_launch(void* const* d_in, const int* in_sizes, int n_in,
                              void* d_out, int out_size, void* d_ws, size_t ws_size,
                              hipStream_t stream) {
    const float* boxes  = (const float*)d_in[0];   // (1000, 320)
    const float* scores = (const float*)d_in[1];   // (1000, 81)
    const int*   imh    = (const int*)d_in[2];
    const int*   imw    = (const int*)d_in[3];
    float* out = (float*)d_out;

    // ws layout (16B-aligned chunks)
    unsigned* cnt       = (unsigned*)d_ws;                      // 320 B @ 0
    u64*      key_stage = (u64*)((char*)d_ws + 1024);           // 163840 B
    u64*      cand_key  = (u64*)((char*)d_ws + 164864);         // 64000 B
    float4*   cand_box  = (float4*)((char*)d_ws + 228864);      // 128000 B

    hipMemsetAsync(cnt, 0, K * sizeof(unsigned), stream);
    gather_kernel<<<(R * KP1 / 4 + 255) / 256, 256, 0, stream>>>(scores, cnt, key_stage);
    nms_kernel<<<K, 64, 0, stream>>>(boxes, imh, imw, cnt, key_stage, cand_key, cand_box);
    topk_kernel<<<1, 256, 0, stream>>>(cand_key, cand_box, out);
}

// Round 5
// 39.335 us; speedup vs baseline: 1.4296x; 1.4296x over previous
//
#include <hip/hip_runtime.h>
#include <hip/hip_bf16.h>

#define R      1000
#define K      80
#define KP1    81
#define CAND   100
#define NC     (K*CAND)
#define VCAP   256
#define SCORE_THRESH 0.05f
#define NMS_THRESH   0.5f

typedef unsigned long long u64;

__device__ __forceinline__ unsigned int ordf(float f) {
    unsigned int u = __float_as_uint(f);
    return (u & 0x80000000u) ? ~u : (u | 0x80000000u);
}
__device__ __forceinline__ float unordf(unsigned int o) {
    unsigned int u = (o & 0x80000000u) ? (o ^ 0x80000000u) : ~o;
    return __uint_as_float(u);
}

// ---------------------------------------------------------------------------
// Wave-0 pipeline: register bitonic sort of (score, ~pos) keys -> boxes from
// LDS (pre-staged by all 4 waves in compacted order) -> uniform-mask greedy
// NMS scan -> emit candidates. Single wave, no barriers.
// ---------------------------------------------------------------------------
template<int NR>
__device__ __forceinline__ void sort_nms_emit(
    int k, int lane, int V,
    u64* skey, const float4* sbox, float4* sboxs,
    u64* __restrict__ cand_key, float4* __restrict__ cand_box)
{
    const u64 lt_mask = (1ull << lane) - 1ull;
    u64 key[NR];
    #pragma unroll
    for (int r = 0; r < NR; ++r) key[r] = skey[r * 64 + lane];

    constexpr int N = NR * 64;
    // ---- bitonic sort, descending (proven R3/R4)
    #pragma unroll
    for (int size = 2; size <= N; size <<= 1) {
        #pragma unroll
        for (int stride = size >> 1; stride > 0; stride >>= 1) {
            if (stride >= 64) {
                const int rs = stride >> 6;
                #pragma unroll
                for (int r = 0; r < NR; ++r) {
                    if ((r & rs) == 0 && (r | rs) < NR) {
                        const int r2 = r | rs;
                        const bool desc = (((r * 64) & size) == 0);
                        u64 a = key[r], b = key[r2];
                        bool sw = desc ? (a < b) : (a > b);
                        if (sw) { key[r] = b; key[r2] = a; }
                    }
                }
            } else {
                #pragma unroll
                for (int r = 0; r < NR; ++r) {
                    u64 part = __shfl_xor(key[r], stride, 64);
                    bool desc = (((r * 64 + lane) & size) == 0);
                    bool lower = ((lane & stride) == 0);
                    bool takeMax = (lower == desc);
                    bool pgt = part > key[r];
                    key[r] = (takeMax == pgt) ? part : key[r];
                }
            }
        }
    }

    // ---- fetch boxes (LDS, staged in compacted order) for sorted entries
    float4 bx[NR]; float sc[NR]; float area[NR];
    #pragma unroll
    for (int r = 0; r < NR; ++r) {
        int i = r * 64 + lane;
        u64 kk = key[r];
        sc[r] = unordf((unsigned)(kk >> 32));
        float4 bb = make_float4(0.f, 0.f, 0.f, 0.f);
        if (i < V) bb = sbox[0xFFFFFFFFu - (unsigned)kk];
        bx[r] = bb;
        area[r] = (bb.z - bb.x) * (bb.w - bb.y);
        sboxs[i] = bb;           // sorted-order copy for broadcast scan
    }

    // ---- greedy NMS: kept[] wave-uniform => loop-carried chain is SALU only
    u64 kept[NR];
    #pragma unroll
    for (int r = 0; r < NR; ++r) kept[r] = 0ull;

    #pragma unroll
    for (int jc = 0; jc < NR; ++jc) {
        int jmax = V - jc * 64;
        if (jmax > 64) jmax = 64;
        for (int jl = 0; jl < jmax; ++jl) {
            float4 bj = sboxs[jc * 64 + jl];
            float areaB = (bj.z - bj.x) * (bj.w - bj.y);
            u64 hit = 0ull;
            #pragma unroll
            for (int r = 0; r < NR; ++r) {
                float ltx = fmaxf(bx[r].x, bj.x), lty = fmaxf(bx[r].y, bj.y);
                float rbx = fminf(bx[r].z, bj.z), rby = fminf(bx[r].w, bj.w);
                float w = fmaxf(rbx - ltx, 0.f), h = fmaxf(rby - lty, 0.f);
                float inter = w * h;
                float uni = area[r] + areaB - inter;
                float iou = inter / fmaxf(uni, 1e-9f);   // bit-identical to ref
                u64 ball = __ballot(iou > NMS_THRESH);
                hit |= ball & kept[r];
            }
            if (hit == 0ull) kept[jc] |= (1ull << jl);
        }
    }

    // ---- emit kept candidates in rank order; zero-key fillers
    unsigned pre = 0;
    u64* ck = cand_key + (size_t)k * CAND;
    float4* cb = cand_box + (size_t)k * CAND;
    #pragma unroll
    for (int r = 0; r < NR; ++r) {
        u64 m = kept[r];
        bool mine = (m >> lane) & 1ull;
        unsigned rank = pre + (unsigned)__popcll(m & lt_mask);
        if (mine && rank < CAND) {
            unsigned c = (unsigned)(k * CAND + rank);
            ck[rank] = ((u64)ordf(sc[r]) << 32) | (u64)(0xFFFFFFFFu - c);
            cb[rank] = bx[r];
        }
        pre += (unsigned)__popcll(m);
    }
    unsigned T100 = pre < CAND ? pre : CAND;
    for (unsigned s2 = T100 + (unsigned)lane; s2 < CAND; s2 += 64) ck[s2] = 0ull;
}

// ---------------------------------------------------------------------------
// Kernel A: 80 blocks x 256 threads. Phase 1 (all 4 waves): strided score
// gather + ballot compaction + box load/clip into LDS at compacted pos.
// Phase 2 (wave 0 only): sort + NMS + emit. No global counters.
// ---------------------------------------------------------------------------
__global__ __launch_bounds__(256) void nms_all_kernel(
    const float* __restrict__ boxes, const float* __restrict__ scores,
    const int* __restrict__ imh, const int* __restrict__ imw,
    u64* __restrict__ cand_key, float4* __restrict__ cand_box)
{
    const int k = blockIdx.x, tid = threadIdx.x;
    const int lane = tid & 63, w = tid >> 6;

    __shared__ u64    skey[VCAP];
    __shared__ float4 sbox[VCAP];    // compacted order
    __shared__ float4 sboxs[VCAP];   // sorted order (phase 2)
    __shared__ unsigned cnt16[16];

    skey[tid] = 0ull;
    const float Wf = (float)(*imw), Hf = (float)(*imh);

    // ---- phase 1: gather scores (4 waves x 4 iters), ballot counts
    float sv[4]; bool val[4]; unsigned posl[4];
    #pragma unroll
    for (int t = 0; t < 4; ++t) {
        int i = w * 256 + t * 64 + lane;
        float s = -1.f;
        if (i < R) s = scores[i * KP1 + k];
        bool v = s > SCORE_THRESH;
        u64 m = __ballot(v);
        sv[t] = s; val[t] = v;
        posl[t] = (unsigned)__popcll(m & ((1ull << lane) - 1ull));
        if (lane == 0) cnt16[w * 4 + t] = (unsigned)__popcll(m);
    }
    __syncthreads();

    unsigned base4[4] = {0, 0, 0, 0};
    unsigned total = 0;
    #pragma unroll
    for (int x = 0; x < 16; ++x) {
        unsigned cc = cnt16[x];
        #pragma unroll
        for (int t = 0; t < 4; ++t) if (x < w * 4 + t) base4[t] += cc;
        total += cc;
    }
    const int V = total < VCAP ? (int)total : VCAP;

    // scatter keys (score desc, pos asc == row asc: stable compaction) and
    // load+clip boxes into LDS at compacted pos (4 waves -> 4x MLP)
    #pragma unroll
    for (int t = 0; t < 4; ++t) {
        if (val[t]) {
            unsigned pos = base4[t] + posl[t];
            if (pos < VCAP) {
                int i = w * 256 + t * 64 + lane;
                skey[pos] = ((u64)ordf(sv[t]) << 32) | (u64)(0xFFFFFFFFu - pos);
                float4 bb = *(const float4*)(boxes + (size_t)i * (K * 4) + (size_t)k * 4);
                bb.x = fminf(fmaxf(bb.x, 0.f), Wf);
                bb.y = fminf(fmaxf(bb.y, 0.f), Hf);
                bb.z = fminf(fmaxf(bb.z, 0.f), Wf);
                bb.w = fminf(fmaxf(bb.w, 0.f), Hf);
                sbox[pos] = bb;
            }
        }
    }
    __syncthreads();

    if (w != 0) return;   // only wave 0 continues (no further barriers)

    if (V == 0) {
        for (int s2 = lane; s2 < CAND; s2 += 64) cand_key[(size_t)k * CAND + s2] = 0ull;
        return;
    }
    if (V <= 64)       sort_nms_emit<1>(k, lane, V, skey, sbox, sboxs, cand_key, cand_box);
    else if (V <= 128) sort_nms_emit<2>(k, lane, V, skey, sbox, sboxs, cand_key, cand_box);
    else               sort_nms_emit<4>(k, lane, V, skey, sbox, sboxs, cand_key, cand_box);
}

// ---------------------------------------------------------------------------
// Kernel B: exact top-100 of 8000 distinct u64 keys via MSB-first radix
// select (keys in registers), then O(100^2) ranking. Proven R3/R4.
// ---------------------------------------------------------------------------
__global__ __launch_bounds__(256) void topk_kernel(
    const u64* __restrict__ cand_key,
    const float4* __restrict__ cand_box,
    float* __restrict__ out)   // [0..499]=dets (100x5), [500..599]=classes
{
    const int tid  = threadIdx.x;
    const int lane = tid & 63;
    const int w    = tid >> 6;

    __shared__ unsigned hist[4][264];
    __shared__ unsigned wsum[4];
    __shared__ u64 Psh;
    __shared__ unsigned remsh, cntsh;
    __shared__ u64 Wl[128];

    u64 keyv[32];
    #pragma unroll
    for (int j = 0; j < 32; ++j) {
        int idx = tid + 256 * j;
        keyv[j] = (idx < NC) ? cand_key[idx] : 0ull;
    }
    if (tid == 0) { Psh = 0ull; remsh = CAND - 1; cntsh = 0; }

    // bits 31..16 of every nonzero key are 0xFFFF (candidate id < 8192):
    // skip passes 3,2; patch prefix after pass 4.
    const int plist[6] = {7, 6, 5, 4, 1, 0};
    for (int pi = 0; pi < 6; ++pi) {
        const int p = plist[pi];
        const int shift = 8 * p;
        #pragma unroll
        for (int ww = 0; ww < 4; ++ww) hist[ww][tid] = 0;
        __syncthreads();

        u64 pfx = Psh;
        unsigned rem = remsh;
        u64 hmask = (p == 7) ? 0ull : (~0ull << (shift + 8));
        #pragma unroll
        for (int j = 0; j < 32; ++j) {
            u64 kk = keyv[j];
            if (kk != 0ull && ((kk ^ pfx) & hmask) == 0ull)
                atomicAdd(&hist[w][(unsigned)(kk >> shift) & 0xFFu], 1u);
        }
        __syncthreads();

        int b = 255 - tid;
        unsigned v = hist[0][b] + hist[1][b] + hist[2][b] + hist[3][b];
        unsigned inc = v;
        #pragma unroll
        for (int off = 1; off < 64; off <<= 1) {
            unsigned t2 = __shfl_up(inc, off);
            if (lane >= off) inc += t2;
        }
        if (lane == 63) wsum[w] = inc;
        __syncthreads();
        unsigned woff = 0;
        #pragma unroll
        for (int ww = 0; ww < 4; ++ww) if (ww < w) woff += wsum[ww];
        inc += woff;
        unsigned cumG = inc - v;
        if (v > 0 && rem >= cumG && rem < cumG + v) {
            u64 np = pfx | ((u64)(unsigned)b << shift);
            if (p == 4) np |= 0xFFFF0000ull;
            Psh = np;
            remsh = rem - cumG;
        }
        __syncthreads();
    }

    const u64 T = Psh;   // exact rank-99 key
    #pragma unroll
    for (int j = 0; j < 32; ++j) {
        u64 kk = keyv[j];
        if (kk >= T && kk != 0ull) {
            unsigned pos = atomicAdd(&cntsh, 1u);
            if (pos < 128) Wl[pos] = kk;
        }
    }
    __syncthreads();

    if (tid < CAND) {
        u64 my = Wl[tid];
        int r = 0;
        for (int j = 0; j < CAND; ++j) r += (Wl[j] > my) ? 1 : 0;
        unsigned c = 0xFFFFFFFFu - (unsigned)my;
        float s = unordf((unsigned)(my >> 32));
        float4 bb = cand_box[c];
        out[r * 5 + 0] = bb.x;
        out[r * 5 + 1] = bb.y;
        out[r * 5 + 2] = bb.z;
        out[r * 5 + 3] = bb.w;
        out[r * 5 + 4] = s;
        out[500 + r]   = (float)(c / CAND);
    }
}

extern "C" void kernel_launch(void* const* d_in, const int* in_sizes, int n_in,
                              void* d_out, int out_size, void* d_ws, size_t ws_size,
                              hipStream_t stream) {
    const float* boxes  = (const float*)d_in[0];   // (1000, 320)
    const float* scores = (const float*)d_in[1];   // (1000, 81)
    const int*   imh    = (const int*)d_in[2];
    const int*   imw    = (const int*)d_in[3];
    float* out = (float*)d_out;

    u64*    cand_key = (u64*)d_ws;                       // 64000 B @ 0
    float4* cand_box = (float4*)((char*)d_ws + 65536);   // 128000 B @ 64 KiB

    nms_all_kernel<<<K, 256, 0, stream>>>(boxes, scores, imh, imw, cand_key, cand_box);
    topk_kernel<<<1, 256, 0, stream>>>(cand_key, cand_box, out);
}

// Round 6
// 33.763 us; speedup vs baseline: 1.6655x; 1.1650x over previous
//
#include <hip/hip_runtime.h>
#include <hip/hip_bf16.h>

#define R      1000
#define K      80
#define KP1    81
#define CAND   100
#define NC     (K*CAND)
#define VCAP   256
#define SCORE_THRESH 0.05f
#define NMS_THRESH   0.5f

typedef unsigned long long u64;

__device__ unsigned g_ctr = 0;   // module-load zero-init; each launch adds exactly K

__device__ __forceinline__ unsigned int ordf(float f) {
    unsigned int u = __float_as_uint(f);
    return (u & 0x80000000u) ? ~u : (u | 0x80000000u);
}
__device__ __forceinline__ float unordf(unsigned int o) {
    unsigned int u = (o & 0x80000000u) ? (o ^ 0x80000000u) : ~o;
    return __uint_as_float(u);
}

// ---------------------------------------------------------------------------
// Per-class pipeline (whole 256-thread block, NR = ceil(V/64) templated):
//  wave0: register bitonic sort of (score,~pos) keys -> sboxs (sorted boxes)
//  all waves: ballot-matrix build, j-partitioned (no loop-carried deps)
//  wave0: scalar greedy scan (register chain only) -> emit candidates
// ---------------------------------------------------------------------------
template<int NR>
__device__ __forceinline__ void pipeline(
    int k, int tid, int lane, int w, int V,
    u64* skey, const float4* sbox, float4* sboxs, u64* mat,
    u64* __restrict__ cand_key, float4* __restrict__ cand_box)
{
    const u64 lt_mask = (1ull << lane) - 1ull;
    constexpr int N = NR * 64;

    float sc[NR];          // wave0 only: scores of its sorted slots
    if (w == 0) {
        u64 key[NR];
        #pragma unroll
        for (int r = 0; r < NR; ++r) key[r] = skey[r * 64 + lane];

        // ---- bitonic sort, descending (proven R3-R5)
        #pragma unroll
        for (int size = 2; size <= N; size <<= 1) {
            #pragma unroll
            for (int stride = size >> 1; stride > 0; stride >>= 1) {
                if (stride >= 64) {
                    const int rs = stride >> 6;
                    #pragma unroll
                    for (int r = 0; r < NR; ++r) {
                        if ((r & rs) == 0 && (r | rs) < NR) {
                            const int r2 = r | rs;
                            const bool desc = (((r * 64) & size) == 0);
                            u64 a = key[r], b = key[r2];
                            bool sw = desc ? (a < b) : (a > b);
                            if (sw) { key[r] = b; key[r2] = a; }
                        }
                    }
                } else {
                    #pragma unroll
                    for (int r = 0; r < NR; ++r) {
                        u64 part = __shfl_xor(key[r], stride, 64);
                        bool desc = (((r * 64 + lane) & size) == 0);
                        bool lower = ((lane & stride) == 0);
                        bool takeMax = (lower == desc);
                        bool pgt = part > key[r];
                        key[r] = (takeMax == pgt) ? part : key[r];
                    }
                }
            }
        }

        // sorted-order boxes to LDS (zero box beyond V); keep scores in regs
        #pragma unroll
        for (int r = 0; r < NR; ++r) {
            int i = r * 64 + lane;
            u64 kk = key[r];
            sc[r] = unordf((unsigned)(kk >> 32));
            float4 bb = make_float4(0.f, 0.f, 0.f, 0.f);
            if (i < V) bb = sbox[0xFFFFFFFFu - (unsigned)kk];
            sboxs[i] = bb;
        }
    }
    __syncthreads();   // sboxs visible to all waves

    // ---- all waves: full sorted box set into registers
    float4 bx[NR]; float area[NR];
    #pragma unroll
    for (int r = 0; r < NR; ++r) {
        float4 bb = sboxs[r * 64 + lane];
        bx[r] = bb;
        area[r] = (bb.z - bb.x) * (bb.w - bb.y);
    }

    // ---- ballot-matrix build: wave w owns j in [w*Vq, min((w+1)*Vq, V))
    const int Vq = (V + 3) >> 2;
    int jbeg = w * Vq;
    int jend = jbeg + Vq; if (jend > V) jend = V;
    #pragma unroll 2
    for (int j = jbeg; j < jend; ++j) {
        float4 bj = sboxs[j];
        float areaB = (bj.z - bj.x) * (bj.w - bj.y);
        #pragma unroll
        for (int r = 0; r < NR; ++r) {
            float ltx = fmaxf(bx[r].x, bj.x), lty = fmaxf(bx[r].y, bj.y);
            float rbx = fminf(bx[r].z, bj.z), rby = fminf(bx[r].w, bj.w);
            float ww = fmaxf(rbx - ltx, 0.f), hh = fmaxf(rby - lty, 0.f);
            float inter = ww * hh;
            float uni = area[r] + areaB - inter;
            float iou = inter / fmaxf(uni, 1e-9f);   // bit-identical to ref
            mat[j * NR + r] = __ballot(iou > NMS_THRESH);
        }
    }
    __syncthreads();   // mat visible to wave 0

    if (w != 0) return;   // waves 1-3 rejoin at caller's handshake barrier

    // ---- greedy scan: pure register chain, prefetch next row
    u64 kept[NR];
    #pragma unroll
    for (int r = 0; r < NR; ++r) kept[r] = 0ull;
    u64 cur[NR];
    #pragma unroll
    for (int r = 0; r < NR; ++r) cur[r] = mat[r];

    int j = 0;
    #pragma unroll
    for (int jc = 0; jc < NR; ++jc) {
        int jmax = V - jc * 64;
        if (jmax > 64) jmax = 64;
        for (int jl = 0; jl < jmax; ++jl, ++j) {
            u64 nxt[NR];
            #pragma unroll
            for (int r = 0; r < NR; ++r) nxt[r] = mat[(j + 1) * NR + r];
            u64 hit = 0ull;
            #pragma unroll
            for (int r = 0; r < NR; ++r) hit |= cur[r] & kept[r];
            if (hit == 0ull) kept[jc] |= (1ull << jl);   // kept has only i<j bits
            #pragma unroll
            for (int r = 0; r < NR; ++r) cur[r] = nxt[r];
        }
    }

    // ---- emit kept candidates in rank order; zero-key fillers
    unsigned pre = 0;
    u64* ck = cand_key + (size_t)k * CAND;
    float4* cb = cand_box + (size_t)k * CAND;
    #pragma unroll
    for (int r = 0; r < NR; ++r) {
        u64 m = kept[r];
        bool mine = (m >> lane) & 1ull;
        unsigned rank = pre + (unsigned)__popcll(m & lt_mask);
        if (mine && rank < CAND) {
            unsigned c = (unsigned)(k * CAND + rank);
            ck[rank] = ((u64)ordf(sc[r]) << 32) | (u64)(0xFFFFFFFFu - c);
            cb[rank] = bx[r];
        }
        pre += (unsigned)__popcll(m);
    }
    unsigned T100 = pre < CAND ? pre : CAND;
    for (unsigned s2 = T100 + (unsigned)lane; s2 < CAND; s2 += 64) ck[s2] = 0ull;
}

// ---------------------------------------------------------------------------
// Single fused kernel: 80 blocks x 256. Gather/compact -> pipeline -> last
// block (device-global mod-K handshake) runs the exact radix-select top-100.
// ---------------------------------------------------------------------------
__global__ __launch_bounds__(256) void fused_kernel(
    const float* __restrict__ boxes, const float* __restrict__ scores,
    const int* __restrict__ imh, const int* __restrict__ imw,
    u64* __restrict__ cand_key, float4* __restrict__ cand_box,
    float* __restrict__ out)
{
    const int k = blockIdx.x, tid = threadIdx.x;
    const int lane = tid & 63, w = tid >> 6;

    __shared__ u64    skey[VCAP];
    __shared__ float4 sbox[VCAP];        // compacted order
    __shared__ float4 sboxs[VCAP];       // sorted order
    __shared__ u64    mat[(VCAP + 1) * 4];
    __shared__ unsigned cnt16[16];
    __shared__ int lastf;
    __shared__ unsigned hist[4][264];
    __shared__ unsigned wsum[4];
    __shared__ u64 Psh;
    __shared__ unsigned remsh, cntsh;
    __shared__ u64 Wl[128];

    skey[tid] = 0ull;
    const float Wf = (float)(*imw), Hf = (float)(*imh);

    // ---- phase 1: strided score gather (4 waves x 4), ballot compaction,
    //      box load+clip into LDS at compacted pos (proven R3/R5)
    float sv[4]; bool val[4]; unsigned posl[4];
    #pragma unroll
    for (int t = 0; t < 4; ++t) {
        int i = w * 256 + t * 64 + lane;
        float s = -1.f;
        if (i < R) s = scores[i * KP1 + k];
        bool v = s > SCORE_THRESH;
        u64 m = __ballot(v);
        sv[t] = s; val[t] = v;
        posl[t] = (unsigned)__popcll(m & ((1ull << lane) - 1ull));
        if (lane == 0) cnt16[w * 4 + t] = (unsigned)__popcll(m);
    }
    __syncthreads();

    unsigned base4[4] = {0, 0, 0, 0};
    unsigned total = 0;
    #pragma unroll
    for (int x = 0; x < 16; ++x) {
        unsigned cc = cnt16[x];
        #pragma unroll
        for (int t = 0; t < 4; ++t) if (x < w * 4 + t) base4[t] += cc;
        total += cc;
    }
    const int V = total < VCAP ? (int)total : VCAP;

    #pragma unroll
    for (int t = 0; t < 4; ++t) {
        if (val[t]) {
            unsigned pos = base4[t] + posl[t];
            if (pos < VCAP) {
                int i = w * 256 + t * 64 + lane;
                skey[pos] = ((u64)ordf(sv[t]) << 32) | (u64)(0xFFFFFFFFu - pos);
                float4 bb = *(const float4*)(boxes + (size_t)i * (K * 4) + (size_t)k * 4);
                bb.x = fminf(fmaxf(bb.x, 0.f), Wf);
                bb.y = fminf(fmaxf(bb.y, 0.f), Hf);
                bb.z = fminf(fmaxf(bb.z, 0.f), Wf);
                bb.w = fminf(fmaxf(bb.w, 0.f), Hf);
                sbox[pos] = bb;
            }
        }
    }
    __syncthreads();

    // ---- phase 2: sort + matrix + scan + emit (uniform template branch)
    if (V > 0) {
        if (V <= 64)       pipeline<1>(k, tid, lane, w, V, skey, sbox, sboxs, mat, cand_key, cand_box);
        else if (V <= 128) pipeline<2>(k, tid, lane, w, V, skey, sbox, sboxs, mat, cand_key, cand_box);
        else               pipeline<4>(k, tid, lane, w, V, skey, sbox, sboxs, mat, cand_key, cand_box);
    } else {
        if (w == 0)
            for (int s2 = lane; s2 < CAND; s2 += 64) cand_key[(size_t)k * CAND + s2] = 0ull;
        __syncthreads();   // match pipeline's two internal barriers
        __syncthreads();
    }
    __syncthreads();

    // ---- handshake: counter is 0 mod K at every launch start (loader-init +
    //      exactly K increments per launch) => old%K==K-1 marks the last block
    if (tid == 0) {
        __threadfence();
        unsigned old = __hip_atomic_fetch_add(&g_ctr, 1u, __ATOMIC_ACQ_REL, __HIP_MEMORY_SCOPE_AGENT);
        lastf = ((old % (unsigned)K) == (unsigned)(K - 1)) ? 1 : 0;
    }
    __syncthreads();
    if (!lastf) return;
    __threadfence();

    // ---- phase 3: exact top-100 of 8000 distinct keys (proven R3-R5)
    u64 keyv[32];
    #pragma unroll
    for (int j = 0; j < 32; ++j) {
        int idx = tid + 256 * j;
        keyv[j] = (idx < NC) ? cand_key[idx] : 0ull;
    }
    if (tid == 0) { Psh = 0ull; remsh = CAND - 1; cntsh = 0; }

    const int plist[6] = {7, 6, 5, 4, 1, 0};   // bits 31..16 are 0xFFFF: skip
    for (int pi = 0; pi < 6; ++pi) {
        const int p = plist[pi];
        const int shift = 8 * p;
        #pragma unroll
        for (int ww = 0; ww < 4; ++ww) hist[ww][tid] = 0;
        __syncthreads();

        u64 pfx = Psh;
        unsigned rem = remsh;
        u64 hmask = (p == 7) ? 0ull : (~0ull << (shift + 8));
        #pragma unroll
        for (int j = 0; j < 32; ++j) {
            u64 kk = keyv[j];
            if (kk != 0ull && ((kk ^ pfx) & hmask) == 0ull)
                atomicAdd(&hist[w][(unsigned)(kk >> shift) & 0xFFu], 1u);
        }
        __syncthreads();

        int b = 255 - tid;
        unsigned v = hist[0][b] + hist[1][b] + hist[2][b] + hist[3][b];
        unsigned inc = v;
        #pragma unroll
        for (int off = 1; off < 64; off <<= 1) {
            unsigned t2 = __shfl_up(inc, off);
            if (lane >= off) inc += t2;
        }
        if (lane == 63) wsum[w] = inc;
        __syncthreads();
        unsigned woff = 0;
        #pragma unroll
        for (int ww = 0; ww < 4; ++ww) if (ww < w) woff += wsum[ww];
        inc += woff;
        unsigned cumG = inc - v;
        if (v > 0 && rem >= cumG && rem < cumG + v) {
            u64 np = pfx | ((u64)(unsigned)b << shift);
            if (p == 4) np |= 0xFFFF0000ull;
            Psh = np;
            remsh = rem - cumG;
        }
        __syncthreads();
    }

    const u64 T = Psh;   // exact rank-99 key
    #pragma unroll
    for (int j = 0; j < 32; ++j) {
        u64 kk = keyv[j];
        if (kk >= T && kk != 0ull) {
            unsigned pos = atomicAdd(&cntsh, 1u);
            if (pos < 128) Wl[pos] = kk;
        }
    }
    __syncthreads();

    if (tid < CAND) {
        u64 my = Wl[tid];
        int r = 0;
        for (int j = 0; j < CAND; ++j) r += (Wl[j] > my) ? 1 : 0;
        unsigned c = 0xFFFFFFFFu - (unsigned)my;
        float s = unordf((unsigned)(my >> 32));
        float4 bb = cand_box[c];
        out[r * 5 + 0] = bb.x;
        out[r * 5 + 1] = bb.y;
        out[r * 5 + 2] = bb.z;
        out[r * 5 + 3] = bb.w;
        out[r * 5 + 4] = s;
        out[500 + r]   = (float)(c / CAND);
    }
}

extern "C" void kernel_launch(void* const* d_in, const int* in_sizes, int n_in,
                              void* d_out, int out_size, void* d_ws, size_t ws_size,
                              hipStream_t stream) {
    const float* boxes  = (const float*)d_in[0];   // (1000, 320)
    const float* scores = (const float*)d_in[1];   // (1000, 81)
    const int*   imh    = (const int*)d_in[2];
    const int*   imw    = (const int*)d_in[3];
    float* out = (float*)d_out;

    u64*    cand_key = (u64*)d_ws;                       // 64000 B @ 0
    float4* cand_box = (float4*)((char*)d_ws + 65536);   // 128000 B @ 64 KiB

    fused_kernel<<<K, 256, 0, stream>>>(boxes, scores, imh, imw,
                                        cand_key, cand_box, out);
}

// Round 7
// 23.503 us; speedup vs baseline: 2.3925x; 1.4365x over previous
//
#include <hip/hip_runtime.h>
#include <hip/hip_bf16.h>

#define R      1000
#define K      80
#define KP1    81
#define CAND   100
#define NC     (K*CAND)
#define VCAP   256
#define SCORE_THRESH 0.05f
#define NMS_THRESH   0.5f

typedef unsigned long long u64;

__device__ unsigned g_ctr = 0;   // module-load zero-init; each launch adds exactly K

__device__ __forceinline__ unsigned int ordf(float f) {
    unsigned int u = __float_as_uint(f);
    return (u & 0x80000000u) ? ~u : (u | 0x80000000u);
}
__device__ __forceinline__ float unordf(unsigned int o) {
    unsigned int u = (o & 0x80000000u) ? (o ^ 0x80000000u) : ~o;
    return __uint_as_float(u);
}

// Agent-scope coherent access (write-through to device coherence point; no
// wbl2 fences needed for the producer->last-block-consumer handoff).
__device__ __forceinline__ void st_agent_u64(u64* p, u64 v) {
    __hip_atomic_store(p, v, __ATOMIC_RELAXED, __HIP_MEMORY_SCOPE_AGENT);
}
__device__ __forceinline__ u64 ld_agent_u64(const u64* p) {
    return __hip_atomic_load(p, __ATOMIC_RELAXED, __HIP_MEMORY_SCOPE_AGENT);
}
__device__ __forceinline__ void st_box(float4* p, float4 b) {
    union { float f[2]; u64 u; } lo, hi;
    lo.f[0] = b.x; lo.f[1] = b.y; hi.f[0] = b.z; hi.f[1] = b.w;
    st_agent_u64((u64*)p, lo.u);
    st_agent_u64((u64*)p + 1, hi.u);
}
__device__ __forceinline__ float4 ld_box(const float4* p) {
    union { float f[2]; u64 u; } lo, hi;
    lo.u = ld_agent_u64((const u64*)p);
    hi.u = ld_agent_u64((const u64*)p + 1);
    return make_float4(lo.f[0], lo.f[1], hi.f[0], hi.f[1]);
}

// ---------------------------------------------------------------------------
// Per-class pipeline (proven R6): wave0 register bitonic sort -> all-wave
// ballot-matrix build -> wave0 scalar greedy scan -> emit candidates.
// ---------------------------------------------------------------------------
template<int NR>
__device__ __forceinline__ void pipeline(
    int k, int tid, int lane, int w, int V,
    u64* skey, const float4* sbox, float4* sboxs, u64* mat,
    u64* __restrict__ cand_key, float4* __restrict__ cand_box)
{
    const u64 lt_mask = (1ull << lane) - 1ull;
    constexpr int N = NR * 64;

    float sc[NR];
    if (w == 0) {
        u64 key[NR];
        #pragma unroll
        for (int r = 0; r < NR; ++r) key[r] = skey[r * 64 + lane];

        #pragma unroll
        for (int size = 2; size <= N; size <<= 1) {
            #pragma unroll
            for (int stride = size >> 1; stride > 0; stride >>= 1) {
                if (stride >= 64) {
                    const int rs = stride >> 6;
                    #pragma unroll
                    for (int r = 0; r < NR; ++r) {
                        if ((r & rs) == 0 && (r | rs) < NR) {
                            const int r2 = r | rs;
                            const bool desc = (((r * 64) & size) == 0);
                            u64 a = key[r], b = key[r2];
                            bool sw = desc ? (a < b) : (a > b);
                            if (sw) { key[r] = b; key[r2] = a; }
                        }
                    }
                } else {
                    #pragma unroll
                    for (int r = 0; r < NR; ++r) {
                        u64 part = __shfl_xor(key[r], stride, 64);
                        bool desc = (((r * 64 + lane) & size) == 0);
                        bool lower = ((lane & stride) == 0);
                        bool takeMax = (lower == desc);
                        bool pgt = part > key[r];
                        key[r] = (takeMax == pgt) ? part : key[r];
                    }
                }
            }
        }

        #pragma unroll
        for (int r = 0; r < NR; ++r) {
            int i = r * 64 + lane;
            u64 kk = key[r];
            sc[r] = unordf((unsigned)(kk >> 32));
            float4 bb = make_float4(0.f, 0.f, 0.f, 0.f);
            if (i < V) bb = sbox[0xFFFFFFFFu - (unsigned)kk];
            sboxs[i] = bb;
        }
    }
    __syncthreads();

    float4 bx[NR]; float area[NR];
    #pragma unroll
    for (int r = 0; r < NR; ++r) {
        float4 bb = sboxs[r * 64 + lane];
        bx[r] = bb;
        area[r] = (bb.z - bb.x) * (bb.w - bb.y);
    }

    const int Vq = (V + 3) >> 2;
    int jbeg = w * Vq;
    int jend = jbeg + Vq; if (jend > V) jend = V;
    #pragma unroll 2
    for (int j = jbeg; j < jend; ++j) {
        float4 bj = sboxs[j];
        float areaB = (bj.z - bj.x) * (bj.w - bj.y);
        #pragma unroll
        for (int r = 0; r < NR; ++r) {
            float ltx = fmaxf(bx[r].x, bj.x), lty = fmaxf(bx[r].y, bj.y);
            float rbx = fminf(bx[r].z, bj.z), rby = fminf(bx[r].w, bj.w);
            float ww = fmaxf(rbx - ltx, 0.f), hh = fmaxf(rby - lty, 0.f);
            float inter = ww * hh;
            float uni = area[r] + areaB - inter;
            float iou = inter / fmaxf(uni, 1e-9f);   // bit-identical to ref
            mat[j * NR + r] = __ballot(iou > NMS_THRESH);
        }
    }
    __syncthreads();

    if (w != 0) return;

    u64 kept[NR];
    #pragma unroll
    for (int r = 0; r < NR; ++r) kept[r] = 0ull;
    u64 cur[NR];
    #pragma unroll
    for (int r = 0; r < NR; ++r) cur[r] = mat[r];

    int j = 0;
    #pragma unroll
    for (int jc = 0; jc < NR; ++jc) {
        int jmax = V - jc * 64;
        if (jmax > 64) jmax = 64;
        for (int jl = 0; jl < jmax; ++jl, ++j) {
            u64 nxt[NR];
            #pragma unroll
            for (int r = 0; r < NR; ++r) nxt[r] = mat[(j + 1) * NR + r];
            u64 hit = 0ull;
            #pragma unroll
            for (int r = 0; r < NR; ++r) hit |= cur[r] & kept[r];
            if (hit == 0ull) kept[jc] |= (1ull << jl);
            #pragma unroll
            for (int r = 0; r < NR; ++r) cur[r] = nxt[r];
        }
    }

    unsigned pre = 0;
    u64* ck = cand_key + (size_t)k * CAND;
    float4* cb = cand_box + (size_t)k * CAND;
    #pragma unroll
    for (int r = 0; r < NR; ++r) {
        u64 m = kept[r];
        bool mine = (m >> lane) & 1ull;
        unsigned rank = pre + (unsigned)__popcll(m & lt_mask);
        if (mine && rank < CAND) {
            unsigned c = (unsigned)(k * CAND + rank);
            st_agent_u64(&ck[rank], ((u64)ordf(sc[r]) << 32) | (u64)(0xFFFFFFFFu - c));
            st_box(&cb[rank], bx[r]);
        }
        pre += (unsigned)__popcll(m);
    }
    unsigned T100 = pre < CAND ? pre : CAND;
    for (unsigned s2 = T100 + (unsigned)lane; s2 < CAND; s2 += 64)
        st_agent_u64(&ck[s2], 0ull);
}

// ---------------------------------------------------------------------------
// Single fused kernel. __launch_bounds__(256,1): allow high VGPR count so
// keyv[32] and the NR=4 pipeline arrays stay in registers (R6 ran at 44 VGPRs
// => spilled to scratch; that was the hidden latency).
// ---------------------------------------------------------------------------
__global__ __launch_bounds__(256, 1) void fused_kernel(
    const float* __restrict__ boxes, const float* __restrict__ scores,
    const int* __restrict__ imh, const int* __restrict__ imw,
    u64* __restrict__ cand_key, float4* __restrict__ cand_box,
    float* __restrict__ out)
{
    const int k = blockIdx.x, tid = threadIdx.x;
    const int lane = tid & 63, w = tid >> 6;

    __shared__ u64    skey[VCAP];
    __shared__ float4 sbox[VCAP];
    __shared__ float4 sboxs[VCAP];
    __shared__ u64    mat[(VCAP + 1) * 4];
    __shared__ unsigned cnt16[16];
    __shared__ int lastf;
    __shared__ unsigned hist[4][264];
    __shared__ unsigned wsum[4];
    __shared__ u64 Psh;
    __shared__ u64 packsh[4];
    __shared__ unsigned remsh, cntsh;
    __shared__ int donesh;
    __shared__ u64 Wl[128];

    skey[tid] = 0ull;
    const float Wf = (float)(*imw), Hf = (float)(*imh);

    // ---- phase 1: strided score gather + ballot compaction + box load/clip
    float sv[4]; bool val[4]; unsigned posl[4];
    #pragma unroll
    for (int t = 0; t < 4; ++t) {
        int i = w * 256 + t * 64 + lane;
        float s = -1.f;
        if (i < R) s = scores[i * KP1 + k];
        bool v = s > SCORE_THRESH;
        u64 m = __ballot(v);
        sv[t] = s; val[t] = v;
        posl[t] = (unsigned)__popcll(m & ((1ull << lane) - 1ull));
        if (lane == 0) cnt16[w * 4 + t] = (unsigned)__popcll(m);
    }
    __syncthreads();

    unsigned base4[4] = {0, 0, 0, 0};
    unsigned total = 0;
    #pragma unroll
    for (int x = 0; x < 16; ++x) {
        unsigned cc = cnt16[x];
        #pragma unroll
        for (int t = 0; t < 4; ++t) if (x < w * 4 + t) base4[t] += cc;
        total += cc;
    }
    const int V = total < VCAP ? (int)total : VCAP;

    #pragma unroll
    for (int t = 0; t < 4; ++t) {
        if (val[t]) {
            unsigned pos = base4[t] + posl[t];
            if (pos < VCAP) {
                int i = w * 256 + t * 64 + lane;
                skey[pos] = ((u64)ordf(sv[t]) << 32) | (u64)(0xFFFFFFFFu - pos);
                float4 bb = *(const float4*)(boxes + (size_t)i * (K * 4) + (size_t)k * 4);
                bb.x = fminf(fmaxf(bb.x, 0.f), Wf);
                bb.y = fminf(fmaxf(bb.y, 0.f), Hf);
                bb.z = fminf(fmaxf(bb.z, 0.f), Wf);
                bb.w = fminf(fmaxf(bb.w, 0.f), Hf);
                sbox[pos] = bb;
            }
        }
    }
    __syncthreads();

    // ---- phase 2: sort + matrix + scan + emit
    if (V > 0) {
        if (V <= 64)       pipeline<1>(k, tid, lane, w, V, skey, sbox, sboxs, mat, cand_key, cand_box);
        else if (V <= 128) pipeline<2>(k, tid, lane, w, V, skey, sbox, sboxs, mat, cand_key, cand_box);
        else               pipeline<4>(k, tid, lane, w, V, skey, sbox, sboxs, mat, cand_key, cand_box);
    } else {
        if (w == 0)
            for (int s2 = lane; s2 < CAND; s2 += 64)
                st_agent_u64(&cand_key[(size_t)k * CAND + s2], 0ull);
        __syncthreads();
        __syncthreads();
    }
    __syncthreads();   // all coherent stores drained (vmcnt) before handshake

    // ---- handshake: relaxed agent atomic; counter is 0 mod K at launch start
    if (tid == 0) {
        unsigned old = __hip_atomic_fetch_add(&g_ctr, 1u, __ATOMIC_RELAXED, __HIP_MEMORY_SCOPE_AGENT);
        lastf = ((old % (unsigned)K) == (unsigned)(K - 1)) ? 1 : 0;
    }
    __syncthreads();
    if (!lastf) return;

    // ---- phase 3: exact top-100 of 8000 distinct keys (coherent loads)
    u64 keyv[32];
    #pragma unroll
    for (int j = 0; j < 32; ++j) {
        int idx = tid + 256 * j;
        keyv[j] = (idx < NC) ? ld_agent_u64(&cand_key[idx]) : 0ull;
    }

    // pass 7 without atomics: scores in (0.05, 1] => byte7 in {0xBD,0xBE,0xBF}.
    // Packed 21-bit counters (counts <= 8000 < 2^21), shuffle-reduced.
    {
        u64 pack = 0ull;
        #pragma unroll
        for (int j = 0; j < 32; ++j) {
            u64 kk = keyv[j];
            if (kk != 0ull) {
                unsigned b7 = (unsigned)(kk >> 56);
                pack += (b7 == 0xBFu) ? (1ull << 42) : (b7 == 0xBEu) ? (1ull << 21) : 1ull;
            }
        }
        #pragma unroll
        for (int off = 1; off < 64; off <<= 1) pack += __shfl_xor(pack, off, 64);
        if (lane == 0) packsh[w] = pack;
        __syncthreads();
        if (tid == 0) {
            u64 tot = packsh[0] + packsh[1] + packsh[2] + packsh[3];
            unsigned cBF = (unsigned)(tot >> 42) & 0x1FFFFFu;
            unsigned cBE = (unsigned)(tot >> 21) & 0x1FFFFFu;
            unsigned rem = CAND - 1;
            unsigned b, v;
            if (rem < cBF)            { b = 0xBFu; v = cBF; }
            else if (rem < cBF + cBE) { b = 0xBEu; v = cBE; rem -= cBF; }
            else                      { b = 0xBDu; v = (unsigned)tot & 0x1FFFFFu; rem -= cBF + cBE; }
            Psh = (u64)b << 56;
            remsh = rem;
            cntsh = 0;
            donesh = (v == rem + 1) ? 1 : 0;   // min-of-bucket == exact threshold
        }
        __syncthreads();
    }

    // remaining passes (bytes 3,2 are always 0xFFFF: skip; patch at p==4),
    // with early-exit whenever bucket count == rem+1.
    const int plist[5] = {6, 5, 4, 1, 0};
    for (int pi = 0; pi < 5; ++pi) {
        if (donesh) break;
        const int p = plist[pi];
        const int shift = 8 * p;
        #pragma unroll
        for (int ww = 0; ww < 4; ++ww) hist[ww][tid] = 0;
        __syncthreads();

        u64 pfx = Psh;
        unsigned rem = remsh;
        u64 hmask = ~0ull << (shift + 8);
        #pragma unroll
        for (int j = 0; j < 32; ++j) {
            u64 kk = keyv[j];
            if (kk != 0ull && ((kk ^ pfx) & hmask) == 0ull)
                atomicAdd(&hist[w][(unsigned)(kk >> shift) & 0xFFu], 1u);
        }
        __syncthreads();

        int b = 255 - tid;
        unsigned v = hist[0][b] + hist[1][b] + hist[2][b] + hist[3][b];
        unsigned inc = v;
        #pragma unroll
        for (int off = 1; off < 64; off <<= 1) {
            unsigned t2 = __shfl_up(inc, off);
            if (lane >= off) inc += t2;
        }
        if (lane == 63) wsum[w] = inc;
        __syncthreads();
        unsigned woff = 0;
        #pragma unroll
        for (int ww = 0; ww < 4; ++ww) if (ww < w) woff += wsum[ww];
        inc += woff;
        unsigned cumG = inc - v;
        if (v > 0 && rem >= cumG && rem < cumG + v) {
            u64 np = Psh | ((u64)(unsigned)b << shift);
            if (p == 4) np |= 0xFFFF0000ull;
            unsigned rem_new = rem - cumG;
            Psh = np;
            remsh = rem_new;
            donesh = (v == rem_new + 1) ? 1 : 0;
        }
        __syncthreads();
    }

    const u64 T = Psh;   // exact rank-99 threshold (full or zero-extended)
    #pragma unroll
    for (int j = 0; j < 32; ++j) {
        u64 kk = keyv[j];
        if (kk >= T && kk != 0ull) {
            unsigned pos = atomicAdd(&cntsh, 1u);
            if (pos < 128) Wl[pos] = kk;
        }
    }
    __syncthreads();

    if (tid < CAND) {
        u64 my = Wl[tid];
        int r = 0;
        for (int j = 0; j < CAND; ++j) r += (Wl[j] > my) ? 1 : 0;
        unsigned c = 0xFFFFFFFFu - (unsigned)my;
        float s = unordf((unsigned)(my >> 32));
        float4 bb = ld_box(&cand_box[c]);
        out[r * 5 + 0] = bb.x;
        out[r * 5 + 1] = bb.y;
        out[r * 5 + 2] = bb.z;
        out[r * 5 + 3] = bb.w;
        out[r * 5 + 4] = s;
        out[500 + r]   = (float)(c / CAND);
    }
}

extern "C" void kernel_launch(void* const* d_in, const int* in_sizes, int n_in,
                              void* d_out, int out_size, void* d_ws, size_t ws_size,
                              hipStream_t stream) {
    const float* boxes  = (const float*)d_in[0];   // (1000, 320)
    const float* scores = (const float*)d_in[1];   // (1000, 81)
    const int*   imh    = (const int*)d_in[2];
    const int*   imw    = (const int*)d_in[3];
    float* out = (float*)d_out;

    u64*    cand_key = (u64*)d_ws;                       // 64000 B @ 0
    float4* cand_box = (float4*)((char*)d_ws + 65536);   // 128000 B @ 64 KiB

    fused_kernel<<<K, 256, 0, stream>>>(boxes, scores, imh, imw,
                                        cand_key, cand_box, out);
}

// Round 8
// 23.481 us; speedup vs baseline: 2.3948x; 1.0009x over previous
//
#include <hip/hip_runtime.h>
#include <hip/hip_bf16.h>

#define R      1000
#define K      80
#define KP1    81
#define CAND   100
#define NC     (K*CAND)
#define VCAP   256
#define SCORE_THRESH 0.05f
#define NMS_THRESH   0.5f

typedef unsigned long long u64;

__device__ unsigned g_ctr = 0;   // module-load zero-init; each launch adds exactly K

__device__ __forceinline__ unsigned int ordf(float f) {
    unsigned int u = __float_as_uint(f);
    return (u & 0x80000000u) ? ~u : (u | 0x80000000u);
}
__device__ __forceinline__ float unordf(unsigned int o) {
    unsigned int u = (o & 0x80000000u) ? (o ^ 0x80000000u) : ~o;
    return __uint_as_float(u);
}

// Agent-scope coherent access (proven R7): write-through to device coherence
// point; no wbl2 fences needed for producer -> last-block-consumer handoff.
__device__ __forceinline__ void st_agent_u64(u64* p, u64 v) {
    __hip_atomic_store(p, v, __ATOMIC_RELAXED, __HIP_MEMORY_SCOPE_AGENT);
}
__device__ __forceinline__ u64 ld_agent_u64(const u64* p) {
    return __hip_atomic_load(p, __ATOMIC_RELAXED, __HIP_MEMORY_SCOPE_AGENT);
}
__device__ __forceinline__ void st_box(float4* p, float4 b) {
    union { float f[2]; u64 u; } lo, hi;
    lo.f[0] = b.x; lo.f[1] = b.y; hi.f[0] = b.z; hi.f[1] = b.w;
    st_agent_u64((u64*)p, lo.u);
    st_agent_u64((u64*)p + 1, hi.u);
}
__device__ __forceinline__ float4 ld_box(const float4* p) {
    union { float f[2]; u64 u; } lo, hi;
    lo.u = ld_agent_u64((const u64*)p);
    hi.u = ld_agent_u64((const u64*)p + 1);
    return make_float4(lo.f[0], lo.f[1], hi.f[0], hi.f[1]);
}

// ---------------------------------------------------------------------------
// Ballot-matrix build (all 4 waves, j-range partitioned). Garbage boxes at
// positions >= V produce garbage ballot bits, but those bits are only ever
// ANDed with kept-mask bits which are never set at positions >= V -> safe.
// ---------------------------------------------------------------------------
template<int NR>
__device__ __forceinline__ void build_matrix(
    int lane, int w, int V, const float4* sboxs, u64* mat)
{
    float4 bx[NR]; float area[NR];
    #pragma unroll
    for (int r = 0; r < NR; ++r) {
        float4 bb = sboxs[r * 64 + lane];
        bx[r] = bb;
        area[r] = (bb.z - bb.x) * (bb.w - bb.y);
    }
    const int Vq = (V + 3) >> 2;
    int jbeg = w * Vq;
    int jend = jbeg + Vq; if (jend > V) jend = V;
    #pragma unroll 2
    for (int j = jbeg; j < jend; ++j) {
        float4 bj = sboxs[j];
        float areaB = (bj.z - bj.x) * (bj.w - bj.y);
        #pragma unroll
        for (int r = 0; r < NR; ++r) {
            float ltx = fmaxf(bx[r].x, bj.x), lty = fmaxf(bx[r].y, bj.y);
            float rbx = fminf(bx[r].z, bj.z), rby = fminf(bx[r].w, bj.w);
            float ww = fmaxf(rbx - ltx, 0.f), hh = fmaxf(rby - lty, 0.f);
            float inter = ww * hh;
            float uni = area[r] + areaB - inter;
            float iou = inter / fmaxf(uni, 1e-9f);   // bit-identical to ref
            mat[j * NR + r] = __ballot(iou > NMS_THRESH);
        }
    }
}

// ---------------------------------------------------------------------------
// Greedy scan (wave 0 only; uniform scalar chain) + candidate emit.
// ---------------------------------------------------------------------------
template<int NR>
__device__ __forceinline__ void scan_emit(
    int k, int lane, int V,
    const float4* sboxs, const float* sscs, const u64* mat,
    u64* __restrict__ cand_key, float4* __restrict__ cand_box)
{
    const u64 lt_mask = (1ull << lane) - 1ull;

    u64 kept[NR];
    #pragma unroll
    for (int r = 0; r < NR; ++r) kept[r] = 0ull;
    u64 cur[NR];
    #pragma unroll
    for (int r = 0; r < NR; ++r) cur[r] = mat[r];

    int j = 0;
    #pragma unroll
    for (int jc = 0; jc < NR; ++jc) {
        int jmax = V - jc * 64;
        if (jmax > 64) jmax = 64;
        for (int jl = 0; jl < jmax; ++jl, ++j) {
            u64 nxt[NR];
            #pragma unroll
            for (int r = 0; r < NR; ++r) nxt[r] = mat[(j + 1) * NR + r];
            u64 hit = 0ull;
            #pragma unroll
            for (int r = 0; r < NR; ++r) hit |= cur[r] & kept[r];
            if (hit == 0ull) kept[jc] |= (1ull << jl);
            #pragma unroll
            for (int r = 0; r < NR; ++r) cur[r] = nxt[r];
        }
    }

    unsigned pre = 0;
    u64* ck = cand_key + (size_t)k * CAND;
    float4* cb = cand_box + (size_t)k * CAND;
    #pragma unroll
    for (int r = 0; r < NR; ++r) {
        u64 m = kept[r];
        bool mine = (m >> lane) & 1ull;
        unsigned rank = pre + (unsigned)__popcll(m & lt_mask);
        if (mine && rank < CAND) {
            unsigned c = (unsigned)(k * CAND + rank);
            float s = sscs[r * 64 + lane];
            st_agent_u64(&ck[rank], ((u64)ordf(s) << 32) | (u64)(0xFFFFFFFFu - c));
            st_box(&cb[rank], sboxs[r * 64 + lane]);
        }
        pre += (unsigned)__popcll(m);
    }
    unsigned T100 = pre < CAND ? pre : CAND;
    for (unsigned s2 = T100 + (unsigned)lane; s2 < CAND; s2 += 64)
        st_agent_u64(&ck[s2], 0ull);
}

// ---------------------------------------------------------------------------
// Single fused kernel: 80 blocks x 256.
//  P1: score loads (all issued first) -> ballots -> box reg-prefetch ->
//      barrier -> prefix -> compacted scatter (keys + clipped boxes)
//  P2a: all-pairs rank-sort (256 threads, no dependency chain)
//  P2b: ballot matrix (4 waves)   P2c: scan+emit (wave 0)
//  P3: last block (mod-K handshake) -> exact radix-select top-100
// ---------------------------------------------------------------------------
__global__ __launch_bounds__(256, 1) void fused_kernel(
    const float* __restrict__ boxes, const float* __restrict__ scores,
    const int* __restrict__ imh, const int* __restrict__ imw,
    u64* __restrict__ cand_key, float4* __restrict__ cand_box,
    float* __restrict__ out)
{
    const int k = blockIdx.x, tid = threadIdx.x;
    const int lane = tid & 63, w = tid >> 6;

    __shared__ u64    skey[VCAP];
    __shared__ float4 sbox[VCAP];     // compacted order
    __shared__ float4 sboxs[VCAP];    // sorted order
    __shared__ float  sscs[VCAP];     // sorted scores
    __shared__ u64    mat[(VCAP + 1) * 4];
    __shared__ unsigned cnt16[16];
    __shared__ int lastf;
    __shared__ unsigned hist[4][264];
    __shared__ unsigned wsum[4];
    __shared__ u64 Psh;
    __shared__ u64 packsh[4];
    __shared__ unsigned remsh, cntsh;
    __shared__ int donesh;
    __shared__ u64 Wl[128];

    const float Wf = (float)(*imw), Hf = (float)(*imh);

    // ---- P1: issue all 4 score loads first (full MLP), then ballots
    float sv[4];
    #pragma unroll
    for (int t = 0; t < 4; ++t) {
        int i = w * 256 + t * 64 + lane;
        sv[t] = (i < R) ? scores[i * KP1 + k] : -1.f;
    }
    bool val[4]; unsigned posl[4];
    #pragma unroll
    for (int t = 0; t < 4; ++t) {
        bool v = sv[t] > SCORE_THRESH;
        u64 m = __ballot(v);
        val[t] = v;
        posl[t] = (unsigned)__popcll(m & ((1ull << lane) - 1ull));
        if (lane == 0) cnt16[w * 4 + t] = (unsigned)__popcll(m);
    }
    // box prefetch into registers (issues before the barrier; latency hides
    // under barrier + prefix computation)
    float4 rb[4];
    #pragma unroll
    for (int t = 0; t < 4; ++t) {
        if (val[t]) {
            int i = w * 256 + t * 64 + lane;
            rb[t] = *(const float4*)(boxes + (size_t)i * (K * 4) + (size_t)k * 4);
        }
    }
    __syncthreads();

    unsigned base4[4] = {0, 0, 0, 0};
    unsigned total = 0;
    #pragma unroll
    for (int x = 0; x < 16; ++x) {
        unsigned cc = cnt16[x];
        #pragma unroll
        for (int t = 0; t < 4; ++t) if (x < w * 4 + t) base4[t] += cc;
        total += cc;
    }
    const int V = total < VCAP ? (int)total : VCAP;

    #pragma unroll
    for (int t = 0; t < 4; ++t) {
        if (val[t]) {
            unsigned pos = base4[t] + posl[t];
            if (pos < VCAP) {
                skey[pos] = ((u64)ordf(sv[t]) << 32) | (u64)(0xFFFFFFFFu - pos);
                float4 bb = rb[t];
                bb.x = fminf(fmaxf(bb.x, 0.f), Wf);
                bb.y = fminf(fmaxf(bb.y, 0.f), Hf);
                bb.z = fminf(fmaxf(bb.z, 0.f), Wf);
                bb.w = fminf(fmaxf(bb.w, 0.f), Hf);
                sbox[pos] = bb;
            }
        }
    }
    __syncthreads();

    // ---- P2a: all-pairs rank-sort (distinct keys -> exact permutation).
    // All 256 threads, LDS broadcast reads, zero loop-carried dependency.
    if (tid < V) {
        u64 my = skey[tid];
        int rank = 0;
        #pragma unroll 4
        for (int j = 0; j < V; ++j) rank += (skey[j] > my) ? 1 : 0;
        sboxs[rank] = sbox[tid];
        sscs[rank]  = unordf((unsigned)(my >> 32));
    }
    __syncthreads();

    // ---- P2b: ballot matrix (all waves)
    if (V > 0) {
        if (V <= 64)       build_matrix<1>(lane, w, V, sboxs, mat);
        else if (V <= 128) build_matrix<2>(lane, w, V, sboxs, mat);
        else               build_matrix<4>(lane, w, V, sboxs, mat);
    }
    __syncthreads();

    // ---- P2c: greedy scan + emit (wave 0)
    if (w == 0) {
        if (V == 0) {
            for (int s2 = lane; s2 < CAND; s2 += 64)
                st_agent_u64(&cand_key[(size_t)k * CAND + s2], 0ull);
        } else if (V <= 64)  scan_emit<1>(k, lane, V, sboxs, sscs, mat, cand_key, cand_box);
        else if (V <= 128)   scan_emit<2>(k, lane, V, sboxs, sscs, mat, cand_key, cand_box);
        else                 scan_emit<4>(k, lane, V, sboxs, sscs, mat, cand_key, cand_box);
    }
    __syncthreads();   // all coherent stores drained before handshake

    // ---- handshake: relaxed agent atomic; counter == 0 mod K at launch start
    if (tid == 0) {
        unsigned old = __hip_atomic_fetch_add(&g_ctr, 1u, __ATOMIC_RELAXED, __HIP_MEMORY_SCOPE_AGENT);
        lastf = ((old % (unsigned)K) == (unsigned)(K - 1)) ? 1 : 0;
    }
    __syncthreads();
    if (!lastf) return;

    // ---- P3: exact top-100 of 8000 distinct keys (proven R7)
    u64 keyv[32];
    #pragma unroll
    for (int j = 0; j < 32; ++j) {
        int idx = tid + 256 * j;
        keyv[j] = (idx < NC) ? ld_agent_u64(&cand_key[idx]) : 0ull;
    }

    // pass 7 without atomics: scores in (0.05, 1] => byte7 in {0xBD,0xBE,0xBF}
    {
        u64 pack = 0ull;
        #pragma unroll
        for (int j = 0; j < 32; ++j) {
            u64 kk = keyv[j];
            if (kk != 0ull) {
                unsigned b7 = (unsigned)(kk >> 56);
                pack += (b7 == 0xBFu) ? (1ull << 42) : (b7 == 0xBEu) ? (1ull << 21) : 1ull;
            }
        }
        #pragma unroll
        for (int off = 1; off < 64; off <<= 1) pack += __shfl_xor(pack, off, 64);
        if (lane == 0) packsh[w] = pack;
        __syncthreads();
        if (tid == 0) {
            u64 tot = packsh[0] + packsh[1] + packsh[2] + packsh[3];
            unsigned cBF = (unsigned)(tot >> 42) & 0x1FFFFFu;
            unsigned cBE = (unsigned)(tot >> 21) & 0x1FFFFFu;
            unsigned rem = CAND - 1;
            unsigned b, v;
            if (rem < cBF)            { b = 0xBFu; v = cBF; }
            else if (rem < cBF + cBE) { b = 0xBEu; v = cBE; rem -= cBF; }
            else                      { b = 0xBDu; v = (unsigned)tot & 0x1FFFFFu; rem -= cBF + cBE; }
            Psh = (u64)b << 56;
            remsh = rem;
            cntsh = 0;
            donesh = (v == rem + 1) ? 1 : 0;
        }
        __syncthreads();
    }

    const int plist[5] = {6, 5, 4, 1, 0};   // bytes 3,2 always 0xFFFF: skip
    for (int pi = 0; pi < 5; ++pi) {
        if (donesh) break;
        const int p = plist[pi];
        const int shift = 8 * p;
        #pragma unroll
        for (int ww = 0; ww < 4; ++ww) hist[ww][tid] = 0;
        __syncthreads();

        u64 pfx = Psh;
        unsigned rem = remsh;
        u64 hmask = ~0ull << (shift + 8);
        #pragma unroll
        for (int j = 0; j < 32; ++j) {
            u64 kk = keyv[j];
            if (kk != 0ull && ((kk ^ pfx) & hmask) == 0ull)
                atomicAdd(&hist[w][(unsigned)(kk >> shift) & 0xFFu], 1u);
        }
        __syncthreads();

        int b = 255 - tid;
        unsigned v = hist[0][b] + hist[1][b] + hist[2][b] + hist[3][b];
        unsigned inc = v;
        #pragma unroll
        for (int off = 1; off < 64; off <<= 1) {
            unsigned t2 = __shfl_up(inc, off);
            if (lane >= off) inc += t2;
        }
        if (lane == 63) wsum[w] = inc;
        __syncthreads();
        unsigned woff = 0;
        #pragma unroll
        for (int ww = 0; ww < 4; ++ww) if (ww < w) woff += wsum[ww];
        inc += woff;
        unsigned cumG = inc - v;
        if (v > 0 && rem >= cumG && rem < cumG + v) {
            u64 np = Psh | ((u64)(unsigned)b << shift);
            if (p == 4) np |= 0xFFFF0000ull;
            unsigned rem_new = rem - cumG;
            Psh = np;
            remsh = rem_new;
            donesh = (v == rem_new + 1) ? 1 : 0;
        }
        __syncthreads();
    }

    const u64 T = Psh;   // exact rank-99 threshold (full or zero-extended)
    #pragma unroll
    for (int j = 0; j < 32; ++j) {
        u64 kk = keyv[j];
        if (kk >= T && kk != 0ull) {
            unsigned pos = atomicAdd(&cntsh, 1u);
            if (pos < 128) Wl[pos] = kk;
        }
    }
    __syncthreads();

    if (tid < CAND) {
        u64 my = Wl[tid];
        int r = 0;
        for (int j = 0; j < CAND; ++j) r += (Wl[j] > my) ? 1 : 0;
        unsigned c = 0xFFFFFFFFu - (unsigned)my;
        float s = unordf((unsigned)(my >> 32));
        float4 bb = ld_box(&cand_box[c]);
        out[r * 5 + 0] = bb.x;
        out[r * 5 + 1] = bb.y;
        out[r * 5 + 2] = bb.z;
        out[r * 5 + 3] = bb.w;
        out[r * 5 + 4] = s;
        out[500 + r]   = (float)(c / CAND);
    }
}

extern "C" void kernel_launch(void* const* d_in, const int* in_sizes, int n_in,
                              void* d_out, int out_size, void* d_ws, size_t ws_size,
                              hipStream_t stream) {
    const float* boxes  = (const float*)d_in[0];   // (1000, 320)
    const float* scores = (const float*)d_in[1];   // (1000, 81)
    const int*   imh    = (const int*)d_in[2];
    const int*   imw    = (const int*)d_in[3];
    float* out = (float*)d_out;

    u64*    cand_key = (u64*)d_ws;                       // 64000 B @ 0
    float4* cand_box = (float4*)((char*)d_ws + 65536);   // 128000 B @ 64 KiB

    fused_kernel<<<K, 256, 0, stream>>>(boxes, scores, imh, imw,
                                        cand_key, cand_box, out);
}

// Round 9
// 22.178 us; speedup vs baseline: 2.5354x; 1.0587x over previous
//
#include <hip/hip_runtime.h>
#include <hip/hip_bf16.h>

#define R      1000
#define K      80
#define KP1    81
#define CAND   100
#define NC     (K*CAND)
#define VCAP   256
#define SCORE_THRESH 0.05f
#define NMS_THRESH   0.5f

typedef unsigned long long u64;

__device__ unsigned g_ctr = 0;   // module-load zero-init; each launch adds exactly K

__device__ __forceinline__ unsigned int ordf(float f) {
    unsigned int u = __float_as_uint(f);
    return (u & 0x80000000u) ? ~u : (u | 0x80000000u);
}
__device__ __forceinline__ float unordf(unsigned int o) {
    unsigned int u = (o & 0x80000000u) ? (o ^ 0x80000000u) : ~o;
    return __uint_as_float(u);
}

// Agent-scope coherent access (proven R7/R8)
__device__ __forceinline__ void st_agent_u64(u64* p, u64 v) {
    __hip_atomic_store(p, v, __ATOMIC_RELAXED, __HIP_MEMORY_SCOPE_AGENT);
}
__device__ __forceinline__ u64 ld_agent_u64(const u64* p) {
    return __hip_atomic_load(p, __ATOMIC_RELAXED, __HIP_MEMORY_SCOPE_AGENT);
}
__device__ __forceinline__ void st_box(float4* p, float4 b) {
    union { float f[2]; u64 u; } lo, hi;
    lo.f[0] = b.x; lo.f[1] = b.y; hi.f[0] = b.z; hi.f[1] = b.w;
    st_agent_u64((u64*)p, lo.u);
    st_agent_u64((u64*)p + 1, hi.u);
}
__device__ __forceinline__ float4 ld_box(const float4* p) {
    union { float f[2]; u64 u; } lo, hi;
    lo.u = ld_agent_u64((const u64*)p);
    hi.u = ld_agent_u64((const u64*)p + 1);
    return make_float4(lo.f[0], lo.f[1], hi.f[0], hi.f[1]);
}

// ---------------------------------------------------------------------------
// Ballot-matrix build (proven R6-R8)
// ---------------------------------------------------------------------------
template<int NR>
__device__ __forceinline__ void build_matrix(
    int lane, int w, int V, const float4* sboxs, u64* mat)
{
    float4 bx[NR]; float area[NR];
    #pragma unroll
    for (int r = 0; r < NR; ++r) {
        float4 bb = sboxs[r * 64 + lane];
        bx[r] = bb;
        area[r] = (bb.z - bb.x) * (bb.w - bb.y);
    }
    const int Vq = (V + 3) >> 2;
    int jbeg = w * Vq;
    int jend = jbeg + Vq; if (jend > V) jend = V;
    #pragma unroll 2
    for (int j = jbeg; j < jend; ++j) {
        float4 bj = sboxs[j];
        float areaB = (bj.z - bj.x) * (bj.w - bj.y);
        #pragma unroll
        for (int r = 0; r < NR; ++r) {
            float ltx = fmaxf(bx[r].x, bj.x), lty = fmaxf(bx[r].y, bj.y);
            float rbx = fminf(bx[r].z, bj.z), rby = fminf(bx[r].w, bj.w);
            float ww = fmaxf(rbx - ltx, 0.f), hh = fmaxf(rby - lty, 0.f);
            float inter = ww * hh;
            float uni = area[r] + areaB - inter;
            float iou = inter / fmaxf(uni, 1e-9f);   // bit-identical to ref
            mat[j * NR + r] = __ballot(iou > NMS_THRESH);
        }
    }
}

// ---------------------------------------------------------------------------
// Greedy scan (wave 0 only) + candidate emit (proven R6-R8)
// ---------------------------------------------------------------------------
template<int NR>
__device__ __forceinline__ void scan_emit(
    int k, int lane, int V,
    const float4* sboxs, const float* sscs, const u64* mat,
    u64* __restrict__ cand_key, float4* __restrict__ cand_box)
{
    const u64 lt_mask = (1ull << lane) - 1ull;

    u64 kept[NR];
    #pragma unroll
    for (int r = 0; r < NR; ++r) kept[r] = 0ull;
    u64 cur[NR];
    #pragma unroll
    for (int r = 0; r < NR; ++r) cur[r] = mat[r];

    int j = 0;
    #pragma unroll
    for (int jc = 0; jc < NR; ++jc) {
        int jmax = V - jc * 64;
        if (jmax > 64) jmax = 64;
        for (int jl = 0; jl < jmax; ++jl, ++j) {
            u64 nxt[NR];
            #pragma unroll
            for (int r = 0; r < NR; ++r) nxt[r] = mat[(j + 1) * NR + r];
            u64 hit = 0ull;
            #pragma unroll
            for (int r = 0; r < NR; ++r) hit |= cur[r] & kept[r];
            if (hit == 0ull) kept[jc] |= (1ull << jl);
            #pragma unroll
            for (int r = 0; r < NR; ++r) cur[r] = nxt[r];
        }
    }

    unsigned pre = 0;
    u64* ck = cand_key + (size_t)k * CAND;
    float4* cb = cand_box + (size_t)k * CAND;
    #pragma unroll
    for (int r = 0; r < NR; ++r) {
        u64 m = kept[r];
        bool mine = (m >> lane) & 1ull;
        unsigned rank = pre + (unsigned)__popcll(m & lt_mask);
        if (mine && rank < CAND) {
            unsigned c = (unsigned)(k * CAND + rank);
            float s = sscs[r * 64 + lane];
            st_agent_u64(&ck[rank], ((u64)ordf(s) << 32) | (u64)(0xFFFFFFFFu - c));
            st_box(&cb[rank], sboxs[r * 64 + lane]);
        }
        pre += (unsigned)__popcll(m);
    }
    unsigned T100 = pre < CAND ? pre : CAND;
    for (unsigned s2 = T100 + (unsigned)lane; s2 < CAND; s2 += 64)
        st_agent_u64(&ck[s2], 0ull);
}

// ---------------------------------------------------------------------------
// Single fused kernel: 80 blocks x 256.
//  P1/P2: per-class gather->rank-sort->matrix->scan->emit (proven R8)
//  P3 (last block): ONE 768-bin histogram over 16-bit key prefix ->
//    threshold bin -> direct extraction + exact rank-select (common case);
//    radix fallback from byte 5 if threshold bin is huge.
// ---------------------------------------------------------------------------
__global__ __launch_bounds__(256, 1) void fused_kernel(
    const float* __restrict__ boxes, const float* __restrict__ scores,
    const int* __restrict__ imh, const int* __restrict__ imw,
    u64* __restrict__ cand_key, float4* __restrict__ cand_box,
    float* __restrict__ out)
{
    const int k = blockIdx.x, tid = threadIdx.x;
    const int lane = tid & 63, w = tid >> 6;

    __shared__ u64    skey[VCAP];
    __shared__ float4 sbox[VCAP];     // compacted order
    __shared__ float4 sboxs[VCAP];    // sorted order
    __shared__ float  sscs[VCAP];     // sorted scores
    __shared__ u64    mat[(VCAP + 1) * 4];
    __shared__ unsigned cnt16[16];
    __shared__ int lastf;
    __shared__ unsigned h768[768];
    __shared__ unsigned hist[4][264];
    __shared__ unsigned wsum[4];
    __shared__ u64 Psh;
    __shared__ unsigned remsh, cntsh, nExtsh, Bsh;
    __shared__ int donesh;
    __shared__ u64 Wl[256];

    const float Wf = (float)(*imw), Hf = (float)(*imh);

    // ---- P1: all score loads first (MLP), then ballots, box reg-prefetch
    float sv[4];
    #pragma unroll
    for (int t = 0; t < 4; ++t) {
        int i = w * 256 + t * 64 + lane;
        sv[t] = (i < R) ? scores[i * KP1 + k] : -1.f;
    }
    bool val[4]; unsigned posl[4];
    #pragma unroll
    for (int t = 0; t < 4; ++t) {
        bool v = sv[t] > SCORE_THRESH;
        u64 m = __ballot(v);
        val[t] = v;
        posl[t] = (unsigned)__popcll(m & ((1ull << lane) - 1ull));
        if (lane == 0) cnt16[w * 4 + t] = (unsigned)__popcll(m);
    }
    float4 rb[4];
    #pragma unroll
    for (int t = 0; t < 4; ++t) {
        if (val[t]) {
            int i = w * 256 + t * 64 + lane;
            rb[t] = *(const float4*)(boxes + (size_t)i * (K * 4) + (size_t)k * 4);
        }
    }
    __syncthreads();

    unsigned base4[4] = {0, 0, 0, 0};
    unsigned total = 0;
    #pragma unroll
    for (int x = 0; x < 16; ++x) {
        unsigned cc = cnt16[x];
        #pragma unroll
        for (int t = 0; t < 4; ++t) if (x < w * 4 + t) base4[t] += cc;
        total += cc;
    }
    const int V = total < VCAP ? (int)total : VCAP;

    #pragma unroll
    for (int t = 0; t < 4; ++t) {
        if (val[t]) {
            unsigned pos = base4[t] + posl[t];
            if (pos < VCAP) {
                skey[pos] = ((u64)ordf(sv[t]) << 32) | (u64)(0xFFFFFFFFu - pos);
                float4 bb = rb[t];
                bb.x = fminf(fmaxf(bb.x, 0.f), Wf);
                bb.y = fminf(fmaxf(bb.y, 0.f), Hf);
                bb.z = fminf(fmaxf(bb.z, 0.f), Wf);
                bb.w = fminf(fmaxf(bb.w, 0.f), Hf);
                sbox[pos] = bb;
            }
        }
    }
    __syncthreads();

    // ---- P2a: all-pairs rank-sort (distinct keys -> exact permutation)
    if (tid < V) {
        u64 my = skey[tid];
        int rank = 0;
        #pragma unroll 4
        for (int j = 0; j < V; ++j) rank += (skey[j] > my) ? 1 : 0;
        sboxs[rank] = sbox[tid];
        sscs[rank]  = unordf((unsigned)(my >> 32));
    }
    __syncthreads();

    // ---- P2b: ballot matrix (all waves)
    if (V > 0) {
        if (V <= 64)       build_matrix<1>(lane, w, V, sboxs, mat);
        else if (V <= 128) build_matrix<2>(lane, w, V, sboxs, mat);
        else               build_matrix<4>(lane, w, V, sboxs, mat);
    }
    __syncthreads();

    // ---- P2c: greedy scan + emit (wave 0)
    if (w == 0) {
        if (V == 0) {
            for (int s2 = lane; s2 < CAND; s2 += 64)
                st_agent_u64(&cand_key[(size_t)k * CAND + s2], 0ull);
        } else if (V <= 64)  scan_emit<1>(k, lane, V, sboxs, sscs, mat, cand_key, cand_box);
        else if (V <= 128)   scan_emit<2>(k, lane, V, sboxs, sscs, mat, cand_key, cand_box);
        else                 scan_emit<4>(k, lane, V, sboxs, sscs, mat, cand_key, cand_box);
    }
    __syncthreads();   // coherent stores drained before handshake

    // ---- handshake (proven R6-R8)
    if (tid == 0) {
        unsigned old = __hip_atomic_fetch_add(&g_ctr, 1u, __ATOMIC_RELAXED, __HIP_MEMORY_SCOPE_AGENT);
        lastf = ((old % (unsigned)K) == (unsigned)(K - 1)) ? 1 : 0;
    }
    __syncthreads();
    if (!lastf) return;

    // ---- P3: exact top-100 of 8000 distinct keys
    u64 keyv[32];
    #pragma unroll
    for (int j = 0; j < 32; ++j) {
        int idx = tid + 256 * j;
        keyv[j] = (idx < NC) ? ld_agent_u64(&cand_key[idx]) : 0ull;
    }

    // one-pass 768-bin histogram over bits 63..48; byte7 in {0xBD,0xBE,0xBF}
    #pragma unroll
    for (int x = 0; x < 3; ++x) h768[x * 256 + tid] = 0;
    __syncthreads();
    #pragma unroll
    for (int j = 0; j < 32; ++j) {
        u64 kk = keyv[j];
        if (kk != 0ull)
            atomicAdd(&h768[(unsigned)(kk >> 48) - 0xBD00u], 1u);
    }
    __syncthreads();

    // suffix-scan (bin-descending) to locate the rank-99 threshold bin
    {
        unsigned h0 = h768[3 * tid], h1 = h768[3 * tid + 1], h2 = h768[3 * tid + 2];
        unsigned local = h0 + h1 + h2;
        unsigned inc = local;   // inclusive suffix over lanes (lane l: sum l..63)
        #pragma unroll
        for (int off = 1; off < 64; off <<= 1) {
            unsigned v = __shfl_down(inc, off);
            if (lane + off < 64) inc += v;
        }
        if (lane == 0) wsum[w] = inc;   // wave total
        __syncthreads();
        unsigned wafter = 0;
        #pragma unroll
        for (int ww = 0; ww < 4; ++ww) if (ww > w) wafter += wsum[ww];
        unsigned after = inc - local + wafter;   // keys in bins > 3*tid+2

        unsigned G2 = after;
        unsigned G1 = after + h2;
        unsigned G0 = after + h2 + h1;
        if (h2 && G2 <= CAND - 1 && CAND - 1 < G2 + h2) {
            Bsh = 3 * tid + 2; remsh = CAND - 1 - G2; nExtsh = G2 + h2; cntsh = 0; donesh = 0;
        }
        if (h1 && G1 <= CAND - 1 && CAND - 1 < G1 + h1) {
            Bsh = 3 * tid + 1; remsh = CAND - 1 - G1; nExtsh = G1 + h1; cntsh = 0; donesh = 0;
        }
        if (h0 && G0 <= CAND - 1 && CAND - 1 < G0 + h0) {
            Bsh = 3 * tid;     remsh = CAND - 1 - G0; nExtsh = G0 + h0; cntsh = 0; donesh = 0;
        }
        __syncthreads();
    }

    const unsigned B16 = Bsh + 0xBD00u;

    if (nExtsh <= 256) {
        // ---- common case: extract all keys >= bin floor, exact rank-select
        #pragma unroll
        for (int j = 0; j < 32; ++j) {
            u64 kk = keyv[j];
            if (kk != 0ull && (unsigned)(kk >> 48) >= B16) {
                unsigned pos = atomicAdd(&cntsh, 1u);
                Wl[pos] = kk;
            }
        }
        __syncthreads();
        const int n = (int)nExtsh;
        if (tid < n) {
            u64 my = Wl[tid];
            int r = 0;
            for (int j = 0; j < n; ++j) r += (Wl[j] > my) ? 1 : 0;
            if (r < CAND) {
                unsigned c = 0xFFFFFFFFu - (unsigned)my;
                float s = unordf((unsigned)(my >> 32));
                float4 bb = ld_box(&cand_box[c]);
                out[r * 5 + 0] = bb.x;
                out[r * 5 + 1] = bb.y;
                out[r * 5 + 2] = bb.z;
                out[r * 5 + 3] = bb.w;
                out[r * 5 + 4] = s;
                out[500 + r]   = (float)(c / CAND);
            }
        }
        return;
    }

    // ---- rare fallback: radix select continuing at byte 5 (prefix = B16)
    if (tid == 0) Psh = (u64)B16 << 48;
    __syncthreads();

    const int plist[4] = {5, 4, 1, 0};   // bytes 3,2 always 0xFFFF: skip
    for (int pi = 0; pi < 4; ++pi) {
        if (donesh) break;
        const int p = plist[pi];
        const int shift = 8 * p;
        #pragma unroll
        for (int ww = 0; ww < 4; ++ww) hist[ww][tid] = 0;
        __syncthreads();

        u64 pfx = Psh;
        unsigned rem = remsh;
        u64 hmask = ~0ull << (shift + 8);
        #pragma unroll
        for (int j = 0; j < 32; ++j) {
            u64 kk = keyv[j];
            if (kk != 0ull && ((kk ^ pfx) & hmask) == 0ull)
                atomicAdd(&hist[w][(unsigned)(kk >> shift) & 0xFFu], 1u);
        }
        __syncthreads();

        int b = 255 - tid;
        unsigned v = hist[0][b] + hist[1][b] + hist[2][b] + hist[3][b];
        unsigned inc = v;
        #pragma unroll
        for (int off = 1; off < 64; off <<= 1) {
            unsigned t2 = __shfl_up(inc, off);
            if (lane >= off) inc += t2;
        }
        if (lane == 63) wsum[w] = inc;
        __syncthreads();
        unsigned woff = 0;
        #pragma unroll
        for (int ww = 0; ww < 4; ++ww) if (ww < w) woff += wsum[ww];
        inc += woff;
        unsigned cumG = inc - v;
        if (v > 0 && rem >= cumG && rem < cumG + v) {
            u64 np = Psh | ((u64)(unsigned)b << shift);
            if (p == 4) np |= 0xFFFF0000ull;
            unsigned rem_new = rem - cumG;
            Psh = np;
            remsh = rem_new;
            donesh = (v == rem_new + 1) ? 1 : 0;
        }
        __syncthreads();
    }

    const u64 T = Psh;   // exact rank-99 threshold (full or zero-extended)
    #pragma unroll
    for (int j = 0; j < 32; ++j) {
        u64 kk = keyv[j];
        if (kk >= T && kk != 0ull) {
            unsigned pos = atomicAdd(&cntsh, 1u);
            if (pos < 256) Wl[pos] = kk;
        }
    }
    __syncthreads();

    if (tid < CAND) {
        u64 my = Wl[tid];
        int r = 0;
        for (int j = 0; j < CAND; ++j) r += (Wl[j] > my) ? 1 : 0;
        unsigned c = 0xFFFFFFFFu - (unsigned)my;
        float s = unordf((unsigned)(my >> 32));
        float4 bb = ld_box(&cand_box[c]);
        out[r * 5 + 0] = bb.x;
        out[r * 5 + 1] = bb.y;
        out[r * 5 + 2] = bb.z;
        out[r * 5 + 3] = bb.w;
        out[r * 5 + 4] = s;
        out[500 + r]   = (float)(c / CAND);
    }
}

extern "C" void kernel_launch(void* const* d_in, const int* in_sizes, int n_in,
                              void* d_out, int out_size, void* d_ws, size_t ws_size,
                              hipStream_t stream) {
    const float* boxes  = (const float*)d_in[0];   // (1000, 320)
    const float* scores = (const float*)d_in[1];   // (1000, 81)
    const int*   imh    = (const int*)d_in[2];
    const int*   imw    = (const int*)d_in[3];
    float* out = (float*)d_out;

    u64*    cand_key = (u64*)d_ws;                       // 64000 B @ 0
    float4* cand_box = (float4*)((char*)d_ws + 65536);   // 128000 B @ 64 KiB

    fused_kernel<<<K, 256, 0, stream>>>(boxes, scores, imh, imw,
                                        cand_key, cand_box, out);
}